// Round 10
// baseline (547.358 us; speedup 1.0000x reference)
//
#include <hip/hip_runtime.h>
#include <hip/hip_bf16.h>
#include <math.h>

// KoLeo loss, MI355X. Fused normalize -> bf16 fragment repack -> MFMA gram
// row-max (never materializes the 16384^2 gram) -> log/mean epilogue.
//
// v10: LDS caps occupancy at 1 block/CU (96KB) => VGPR budget is 512/wave.
// Spend it: 4 independent MFMA chains per wave (2 i-tiles x 2 j-tiles,
// covers ~128cyc dependent-MFMA latency at 1 wave/SIMD) + T15 acc
// double-buffer (epilogue of unit s-1 interleaves into MFMA(s) issue slots)
// + counted-vmcnt(9) triple-buffer staging (proven R8/R9 scheme) + zc trick.
// Unit = 256i x 64j, 8320 triangular units, 32.5 per block, 256 blocks=1/CU.
//
// F layout (32-row tiles): chunk(t32,ks,lane) = t32*1024 + ks*64 + lane,
//   16B chunk = 8 bf16 of xn[t32*32 + (lane&31)][ks*16 + (lane>>5)*8 .. +7].
// == mfma_f32_32x32x16_bf16 A/B fragment layout -> linear coalesced staging.
// D = mfma(bfr_i, af_j): col=lane&31 -> j_local, row=(r&3)+8(r>>2)+4(lane>>5) -> i_local.

typedef __attribute__((ext_vector_type(8))) short bf16x8;    // 8 bf16 = 4 VGPR
typedef __attribute__((ext_vector_type(16))) float f32x16;   // 32x32 acc

#define NROWS 16384
#define NDIM  256
#define NBLK  256

// ---------------- K0: row 1/norm ----------------
__global__ __launch_bounds__(256) void knorm(const float* __restrict__ x,
                                             float* __restrict__ rn) {
    int wid = threadIdx.x >> 6, lane = threadIdx.x & 63;
    int row = blockIdx.x * 4 + wid;
    const float4* xr = (const float4*)(x + (size_t)row * NDIM);
    float4 v = xr[lane];
    float ss = v.x * v.x + v.y * v.y + v.z * v.z + v.w * v.w;
    #pragma unroll
    for (int m = 1; m < 64; m <<= 1) ss += __shfl_xor(ss, m, 64);
    if (lane == 0) rn[row] = 1.0f / fmaxf(sqrtf(ss), 1e-12f);
}

// ---------------- K1: normalize + pack to 32x32 fragment layout -----------
__device__ inline unsigned bf_rne(float f) {
    union { float f; unsigned u; } c; c.f = f;
    return (c.u + 0x7FFFu + ((c.u >> 16) & 1u)) >> 16;
}
__device__ inline unsigned pack2(float lo, float hi) {
    return bf_rne(lo) | (bf_rne(hi) << 16);
}

__global__ __launch_bounds__(256) void kpack(const float* __restrict__ x,
                                             const float* __restrict__ rn,
                                             uint4* __restrict__ F) {
    int g = blockIdx.x * 256 + threadIdx.x;
    int t32  = g >> 10;
    int rem  = g & 1023;
    int ks   = rem >> 6;
    int lane = rem & 63;
    int row  = t32 * 32 + (lane & 31);
    int kb   = ks * 16 + (lane >> 5) * 8;
    float s = rn[row];
    const float4* xr = (const float4*)(x + (size_t)row * NDIM + kb);
    float4 a = xr[0], b = xr[1];
    uint4 o;
    o.x = pack2(a.x * s, a.y * s);
    o.y = pack2(a.z * s, a.w * s);
    o.z = pack2(b.x * s, b.y * s);
    o.w = pack2(b.z * s, b.w * s);
    F[g] = o;
}

// ---------------- helpers ----------------
__device__ inline void stage16(const uint4* __restrict__ g, const uint4* l) {
    __builtin_amdgcn_global_load_lds(
        (const __attribute__((address_space(1))) unsigned*)g,
        (__attribute__((address_space(3))) unsigned*)l, 16, 0, 0);
}

__device__ inline unsigned fkey(float f) {          // order-preserving key
    unsigned u = __builtin_bit_cast(unsigned, f);
    return (u & 0x80000000u) ? ~u : (u | 0x80000000u);
}

template<int CTRL>                                  // DPP rotate within 16-lane row
__device__ inline float dpp_rot(float x) {
    int xi = __builtin_bit_cast(int, x);
    int yi = __builtin_amdgcn_update_dpp(xi, xi, CTRL, 0xF, 0xF, false);
    return __builtin_bit_cast(float, yi);
}

// ---------------- K2: pipelined symmetric gram + two-sided max ------------
// 256 blocks x 256 threads (4 waves, 1 block/CU). Unit = 256 i x 64 j rows.
__global__ __launch_bounds__(256, 1) void kmax(const bf16x8* __restrict__ F,
                                               unsigned* __restrict__ rowcand) {
    __shared__ uint4 sbuf[3][2048];                 // 3 x 32KB j-pair buffers
    __shared__ uint4 dump[64];                      // pad-load target (dead)
    uint4* sbuf0 = &sbuf[0][0];

    const int tid  = threadIdx.x;
    const int wid  = tid >> 6;                      // 0..3
    const int lane = tid & 63;
    const int L    = lane & 31;
    const int hi   = lane >> 5;
    const uint4* F4 = (const uint4*)F;

    // XCD-chunked bijective swizzle (256 % 8 == 0)
    const int b  = ((blockIdx.x & 7) << 5) | (blockIdx.x >> 3);
    // 8320 units / 256 blocks = 32.5
    const int u0   = (b * 65) >> 1;
    const int uend = ((b + 1) * 65) >> 1;

    // decode u0 -> (cib, cjp): P(ib) = 2*ib*(129-ib); jp in [4*ib, 256)
    int cib = 0;
    while (2 * (cib + 1) * (129 - (cib + 1)) <= u0) ++cib;
    int cjp = 4 * cib + (u0 - 2 * cib * (129 - cib));

    bf16x8 bfr0[16], bfr1[16];                      // 2 i-tiles, 128 VGPR
    int lib = -1;                                   // loaded i-block

    auto stage_unit = [&](int jp, uint4* dst) {     // 8 x 16B per thread
        const uint4* gp = F4 + (size_t)jp * 2048;
        #pragma unroll
        for (int q = 0; q < 8; ++q)
            stage16(gp + q * 256 + tid, dst + q * 256 + wid * 64);
    };
    auto stepc = [](int& ib, int& jp) {
        if (++jp == 256) { if (ib < 63) { ++ib; jp = 4 * ib; } else jp = 255; }
    };

    // prologue: stage(u0)[8], pad[1], stage(u0+1)[8] -> vmcnt(9) uniform
    int sib = cib, sjp = cjp;
    stage_unit(sjp, sbuf0);
    stage16(F4 + tid, dump);
    stepc(sib, sjp);
    stage_unit(sjp, sbuf0 + 2048);

    float rm0[16], rm1[16];
    #pragma unroll
    for (int r = 0; r < 16; ++r) { rm0[r] = -1e30f; rm1[r] = -1e30f; }

    const bool dvalid = (((L >> 2) & 1) == hi);     // lane holds a diag elem
    const int  dreg   = (L & 3) | ((L >> 3) << 2);  // ...at this acc reg
    const f32x16 zc = {0.f};                        // shared zero C operand

    auto flush_i = [&](int fib) {                   // fold rm over j, flush
        #pragma unroll
        for (int r = 0; r < 16; ++r) {
            float a = rm0[r];
            a = fmaxf(a, dpp_rot<0x121>(a));
            a = fmaxf(a, dpp_rot<0x122>(a));
            a = fmaxf(a, dpp_rot<0x124>(a));
            a = fmaxf(a, dpp_rot<0x128>(a));
            rm0[r] = fmaxf(a, __shfl_xor(a, 16, 64));
            float c = rm1[r];
            c = fmaxf(c, dpp_rot<0x121>(c));
            c = fmaxf(c, dpp_rot<0x122>(c));
            c = fmaxf(c, dpp_rot<0x124>(c));
            c = fmaxf(c, dpp_rot<0x128>(c));
            rm1[r] = fmaxf(c, __shfl_xor(c, 16, 64));
        }
        float v0 = rm0[0], v1 = rm1[0];
        #pragma unroll
        for (int r = 1; r < 16; ++r) {
            v0 = (dreg == r) ? rm0[r] : v0;         // lane picks its i-row
            v1 = (dreg == r) ? rm1[r] : v1;
        }
        if (dvalid) {
            int base = fib * 256 + wid * 64;
            atomicMax(&rowcand[base + L],      fkey(v0));
            atomicMax(&rowcand[base + 32 + L], fkey(v1));
        }
    };

    // epilogue for prev unit (acc set e**, meta pjp/pd/pib)
    auto EPI = [&](f32x16& e00, f32x16& e01, f32x16& e10, f32x16& e11,
                   int pjp, bool pd, int pib) {
        float jm0 = -1e30f, jm1 = -1e30f;
        if (pd) {                                   // diag unit (wave-uniform)
            #pragma unroll
            for (int r = 0; r < 16; ++r) {
                float v00 = e00[r], v11 = e11[r];
                bool dr = dvalid && (r == dreg);
                if (dr) { v00 = -1e30f; v11 = -1e30f; }
                rm0[r] = fmaxf(rm0[r], fmaxf(v00, e01[r]));
                rm1[r] = fmaxf(rm1[r], fmaxf(e10[r], v11));
                jm0 = fmaxf(jm0, fmaxf(v00, e10[r]));
                jm1 = fmaxf(jm1, fmaxf(e01[r], v11));
            }
        } else {
            #pragma unroll
            for (int r = 0; r < 16; ++r) {
                rm0[r] = fmaxf(rm0[r], fmaxf(e00[r], e01[r]));
                rm1[r] = fmaxf(rm1[r], fmaxf(e10[r], e11[r]));
                jm0 = fmaxf(jm0, fmaxf(e00[r], e10[r]));
                jm1 = fmaxf(jm1, fmaxf(e01[r], e11[r]));
            }
        }
        jm0 = fmaxf(jm0, __shfl_xor(jm0, 32, 64));  // merge i-halves
        jm1 = fmaxf(jm1, __shfl_xor(jm1, 32, 64));
        float js = hi ? jm1 : jm0;
        atomicMax(&rowcand[pjp * 64 + lane], fkey(js));
        if (pib != cib) {                           // prev closed its i-block
            flush_i(pib);
            #pragma unroll
            for (int r = 0; r < 16; ++r) { rm0[r] = -1e30f; rm1[r] = -1e30f; }
        }
    };

    int bsel = 0;
    auto MFMA_UNIT = [&](f32x16& d00, f32x16& d01, f32x16& d10, f32x16& d11) {
        const uint4* sb = sbuf0 + (size_t)bsel * 2048;
        {
            bf16x8 af0 = *(const bf16x8*)(sb + lane);
            bf16x8 af1 = *(const bf16x8*)(sb + 1024 + lane);
            d00 = __builtin_amdgcn_mfma_f32_32x32x16_bf16(bfr0[0], af0, zc, 0, 0, 0);
            d10 = __builtin_amdgcn_mfma_f32_32x32x16_bf16(bfr1[0], af0, zc, 0, 0, 0);
            d01 = __builtin_amdgcn_mfma_f32_32x32x16_bf16(bfr0[0], af1, zc, 0, 0, 0);
            d11 = __builtin_amdgcn_mfma_f32_32x32x16_bf16(bfr1[0], af1, zc, 0, 0, 0);
        }
        #pragma unroll
        for (int ks = 1; ks < 16; ++ks) {
            bf16x8 af0 = *(const bf16x8*)(sb + ks * 64 + lane);
            bf16x8 af1 = *(const bf16x8*)(sb + 1024 + ks * 64 + lane);
            d00 = __builtin_amdgcn_mfma_f32_32x32x16_bf16(bfr0[ks], af0, d00, 0, 0, 0);
            d10 = __builtin_amdgcn_mfma_f32_32x32x16_bf16(bfr1[ks], af0, d10, 0, 0, 0);
            d01 = __builtin_amdgcn_mfma_f32_32x32x16_bf16(bfr0[ks], af1, d01, 0, 0, 0);
            d11 = __builtin_amdgcn_mfma_f32_32x32x16_bf16(bfr1[ks], af1, d11, 0, 0, 0);
        }
    };

    f32x16 a00, a01, a10, a11, b00, b01, b10, b11;  // two named acc sets (T15)
    int jpA = 0, ibA = 0, jpB = 0, ibB = 0;
    bool pdA = false, pdB = false;

    auto STEP = [&](f32x16& d00, f32x16& d01, f32x16& d10, f32x16& d11,
                    int& mjp, bool& mpd, int& mib,
                    f32x16& e00, f32x16& e01, f32x16& e10, f32x16& e11,
                    int pjp, bool pd, int pib, bool haveP) {
        asm volatile("s_waitcnt vmcnt(9)" ::: "memory");
        __builtin_amdgcn_s_barrier();
        __builtin_amdgcn_sched_barrier(0);
        if (cib != lib) {                           // reload i-frags (rare)
            int it = cib * 8 + 2 * wid;
            #pragma unroll
            for (int ks = 0; ks < 16; ++ks) {
                bfr0[ks] = F[(it + 0) * 1024 + ks * 64 + lane];
                bfr1[ks] = F[(it + 1) * 1024 + ks * 64 + lane];
            }
            lib = cib;
        }
        mjp = cjp; mpd = (cjp == 4 * cib + wid); mib = cib;
        MFMA_UNIT(d00, d01, d10, d11);
        if (haveP) EPI(e00, e01, e10, e11, pjp, pd, pib);
        else       atomicMax(&rowcand[0], 0u);      // dummy: uniform vmcnt
        __builtin_amdgcn_sched_barrier(0);
        stepc(sib, sjp);
        stage_unit(sjp, sbuf0 + (size_t)((bsel + 2 >= 3) ? bsel - 1 : bsel + 2) * 2048);
        bsel = (bsel + 1 >= 3) ? 0 : bsel + 1;
        stepc(cib, cjp);
    };

    const int n = uend - u0;
    for (int s = 0; s < n; ++s) {
        if (!(s & 1)) STEP(a00, a01, a10, a11, jpA, pdA, ibA,
                           b00, b01, b10, b11, jpB, pdB, ibB, s > 0);
        else          STEP(b00, b01, b10, b11, jpB, pdB, ibB,
                           a00, a01, a10, a11, jpA, pdA, ibA, true);
    }
    if (n & 1) { EPI(a00, a01, a10, a11, jpA, pdA, ibA); flush_i(ibA); }
    else       { EPI(b00, b01, b10, b11, jpB, pdB, ibB); flush_i(ibB); }
    // (possible duplicate flush after EPI's internal flush: atomicMax no-op)
}

// ---------------- K3: loss epilogue (2-stage, deterministic) --------------
__global__ __launch_bounds__(256) void kloss1(const unsigned* __restrict__ rowcand,
                                              float* __restrict__ partial) {
    int i = blockIdx.x * 256 + threadIdx.x;         // 64 blocks x 256
    unsigned k = rowcand[i];
    unsigned u = (k & 0x80000000u) ? (k ^ 0x80000000u) : ~k;
    float gv = __builtin_bit_cast(float, u);
    float d = sqrtf(fmaxf(2.f - 2.f * gv, 0.f));
    float acc = logf(d + 1e-8f);
    #pragma unroll
    for (int m = 1; m < 64; m <<= 1) acc += __shfl_xor(acc, m, 64);
    __shared__ float p[4];
    int wid = threadIdx.x >> 6, lane = threadIdx.x & 63;
    if (lane == 0) p[wid] = acc;
    __syncthreads();
    if (threadIdx.x == 0)
        partial[blockIdx.x] = (p[0] + p[1]) + (p[2] + p[3]);
}

__global__ __launch_bounds__(64) void kloss2(const float* __restrict__ partial,
                                             float* __restrict__ out) {
    float acc = partial[threadIdx.x];
    #pragma unroll
    for (int m = 1; m < 64; m <<= 1) acc += __shfl_xor(acc, m, 64);
    if (threadIdx.x == 0) out[0] = -acc / (float)NROWS;
}

extern "C" void kernel_launch(void* const* d_in, const int* in_sizes, int n_in,
                              void* d_out, int out_size, void* d_ws, size_t ws_size,
                              hipStream_t stream) {
    const float* x = (const float*)d_in[0];
    float* out = (float*)d_out;
    char* ws = (char*)d_ws;

    uint4*    F       = (uint4*)ws;                                 // 8 MiB
    float*    rn      = (float*)(ws + 8u * 1024u * 1024u);          // 64 KiB
    unsigned* rowcand = (unsigned*)(ws + 8u * 1024u * 1024u + 65536u); // 64 KiB
    float*    partial = (float*)(ws + 8u * 1024u * 1024u + 131072u);   // 256 B

    hipMemsetAsync(rowcand, 0, NROWS * sizeof(unsigned), stream);
    knorm<<<NROWS / 4, 256, 0, stream>>>(x, rn);
    kpack<<<(NROWS * NDIM / 8) / 256, 256, 0, stream>>>(x, rn, F);
    kmax <<<NBLK, 256, 0, stream>>>((const bf16x8*)F, rowcand);
    kloss1<<<64, 256, 0, stream>>>(rowcand, partial);
    kloss2<<<1, 64, 0, stream>>>(partial, out);
}

// Round 11
// 100.366 us; speedup vs baseline: 5.4536x; 5.4536x over previous
//
#include <hip/hip_runtime.h>
#include <hip/hip_bf16.h>
#include <math.h>

// KoLeo loss, MI355X. Fused normalize -> bf16 fragment repack -> MFMA gram
// row-max (never materializes the 16384^2 gram) -> log/mean epilogue.
//
// v11: v9's proven skeleton (operand-swapped MFMA, counted-vmcnt, triangular
// symmetric walk, two-sided max) reshaped to PAIR units (256i x 64j):
//   - 4 MFMA chains from ONE acc set (64 VGPR; no T15 -- v10's spill lesson)
//   - half the barrier/EPI iterations of v9 (serial overhead amortizes 2x)
//   - double-buffered LDS (2x32KB) with vmcnt(1): order MFMA -> stage(next)
//     -> EPI(1 atomic); only the atomic is newer than the stage at the wait.
//   - __launch_bounds__(256,1): 512-reg budget, spill-proof; 1 block/CU.
//
// F layout (32-row tiles): chunk(t32,ks,lane) = t32*1024 + ks*64 + lane,
//   16B chunk = 8 bf16 of xn[t32*32 + (lane&31)][ks*16 + (lane>>5)*8 .. +7].
// == mfma_f32_32x32x16_bf16 A/B fragment layout -> linear coalesced staging.
// D = mfma(bfr_i, af_j): col=lane&31 -> j_local, row=(r&3)+8(r>>2)+4(lane>>5)
// -> i_local (verified empirically v8-v10).

typedef __attribute__((ext_vector_type(8))) short bf16x8;    // 8 bf16 = 4 VGPR
typedef __attribute__((ext_vector_type(16))) float f32x16;   // 32x32 acc

#define NROWS 16384
#define NDIM  256
#define NBLK  256
// pair-units: ib in [0,64) (256-row i-panel), jp in [4*ib, 256) (64-row j-pair)
// P(ib) = 2*ib*(129-ib); total 8320 units; 32.5 per block.

// ---------------- K0: row 1/norm ----------------
__global__ __launch_bounds__(256) void knorm(const float* __restrict__ x,
                                             float* __restrict__ rn) {
    int wid = threadIdx.x >> 6, lane = threadIdx.x & 63;
    int row = blockIdx.x * 4 + wid;
    const float4* xr = (const float4*)(x + (size_t)row * NDIM);
    float4 v = xr[lane];
    float ss = v.x * v.x + v.y * v.y + v.z * v.z + v.w * v.w;
    #pragma unroll
    for (int m = 1; m < 64; m <<= 1) ss += __shfl_xor(ss, m, 64);
    if (lane == 0) rn[row] = 1.0f / fmaxf(sqrtf(ss), 1e-12f);
}

// ---------------- K1: normalize + pack to 32x32 fragment layout -----------
__device__ inline unsigned bf_rne(float f) {
    union { float f; unsigned u; } c; c.f = f;
    return (c.u + 0x7FFFu + ((c.u >> 16) & 1u)) >> 16;
}
__device__ inline unsigned pack2(float lo, float hi) {
    return bf_rne(lo) | (bf_rne(hi) << 16);
}

__global__ __launch_bounds__(256) void kpack(const float* __restrict__ x,
                                             const float* __restrict__ rn,
                                             uint4* __restrict__ F) {
    int g = blockIdx.x * 256 + threadIdx.x;
    int t32  = g >> 10;
    int rem  = g & 1023;
    int ks   = rem >> 6;
    int lane = rem & 63;
    int row  = t32 * 32 + (lane & 31);
    int kb   = ks * 16 + (lane >> 5) * 8;
    float s = rn[row];
    const float4* xr = (const float4*)(x + (size_t)row * NDIM + kb);
    float4 a = xr[0], b = xr[1];
    uint4 o;
    o.x = pack2(a.x * s, a.y * s);
    o.y = pack2(a.z * s, a.w * s);
    o.z = pack2(b.x * s, b.y * s);
    o.w = pack2(b.z * s, b.w * s);
    F[g] = o;
}

// ---------------- helpers ----------------
__device__ inline void stage16(const uint4* __restrict__ g, const uint4* l) {
    __builtin_amdgcn_global_load_lds(
        (const __attribute__((address_space(1))) unsigned*)g,
        (__attribute__((address_space(3))) unsigned*)l, 16, 0, 0);
}

__device__ inline unsigned fkey(float f) {          // order-preserving key
    unsigned u = __builtin_bit_cast(unsigned, f);
    return (u & 0x80000000u) ? ~u : (u | 0x80000000u);
}

template<int CTRL>                                  // DPP rotate within 16-lane row
__device__ inline float dpp_rot(float x) {
    int xi = __builtin_bit_cast(int, x);
    int yi = __builtin_amdgcn_update_dpp(xi, xi, CTRL, 0xF, 0xF, false);
    return __builtin_bit_cast(float, yi);
}

// ---------------- K2: pipelined symmetric gram + two-sided max ------------
// 256 blocks x 256 threads (4 waves, 1 block/CU). Unit = 256i x 64j rows.
__global__ __launch_bounds__(256, 1) void kmax(const bf16x8* __restrict__ F,
                                               unsigned* __restrict__ rowcand) {
    __shared__ uint4 sbuf[2][2048];                 // 2 x 32KB j-pair buffers
    __shared__ uint4 dump[64];                      // pad-load target (dead)

    const int tid  = threadIdx.x;
    const int wid  = tid >> 6;                      // 0..3
    const int lane = tid & 63;
    const int L    = lane & 31;
    const int hi   = lane >> 5;
    const uint4* F4 = (const uint4*)F;

    // XCD-chunked bijective swizzle (256 % 8 == 0)
    const int b    = ((blockIdx.x & 7) << 5) | (blockIdx.x >> 3);
    const int u0   = (b * 65) >> 1;                 // 8320/256 = 32.5
    const int uend = ((b + 1) * 65) >> 1;

    // decode u0 -> (cib, cjp)
    int cib = 0;
    while (2 * (cib + 1) * (129 - (cib + 1)) <= u0) ++cib;
    int cjp = 4 * cib + (u0 - 2 * cib * (129 - cib));

    // hoisted i-fragments: tiles {cib*8 + 2wid, +1}, 128 VGPR
    bf16x8 bfr0[16], bfr1[16];
    int lib = cib;
    {
        int it = cib * 8 + 2 * wid;
        #pragma unroll
        for (int ks = 0; ks < 16; ++ks) {
            bfr0[ks] = F[(it + 0) * 1024 + ks * 64 + lane];
            bfr1[ks] = F[(it + 1) * 1024 + ks * 64 + lane];
        }
    }

    // stage cursor + prologue: stage(u0) [8 loads] + 1 dummy atomic
    int sib = cib, sjp = cjp;
    {
        const uint4* gp = F4 + (size_t)cjp * 2048;
        #pragma unroll
        for (int q = 0; q < 8; ++q)
            stage16(gp + q * 256 + tid, &sbuf[0][q * 256 + wid * 64]);
    }
    atomicMax(&rowcand[0], 0u);                     // uniform vmcnt at iter 0

    float rm0[16], rm1[16];
    #pragma unroll
    for (int r = 0; r < 16; ++r) { rm0[r] = -1e30f; rm1[r] = -1e30f; }

    const bool dvalid = (((L >> 2) & 1) == hi);     // lane holds a diag elem
    const int  dreg   = (L & 3) | ((L >> 3) << 2);  // ...at this acc reg
    const f32x16 zc = {0.f};

    auto flush_i = [&](int fib) {                   // fold rm over j, flush
        #pragma unroll
        for (int r = 0; r < 16; ++r) {
            float a = rm0[r];
            a = fmaxf(a, dpp_rot<0x121>(a));
            a = fmaxf(a, dpp_rot<0x122>(a));
            a = fmaxf(a, dpp_rot<0x124>(a));
            a = fmaxf(a, dpp_rot<0x128>(a));
            rm0[r] = fmaxf(a, __shfl_xor(a, 16, 64));
            float c = rm1[r];
            c = fmaxf(c, dpp_rot<0x121>(c));
            c = fmaxf(c, dpp_rot<0x122>(c));
            c = fmaxf(c, dpp_rot<0x124>(c));
            c = fmaxf(c, dpp_rot<0x128>(c));
            rm1[r] = fmaxf(c, __shfl_xor(c, 16, 64));
        }
        float v0 = rm0[0], v1 = rm1[0];
        #pragma unroll
        for (int r = 1; r < 16; ++r) {
            v0 = (dreg == r) ? rm0[r] : v0;         // lane picks its i-row
            v1 = (dreg == r) ? rm1[r] : v1;
        }
        if (dvalid) {
            int base = fib * 256 + wid * 64;
            atomicMax(&rowcand[base + L],      fkey(v0));
            atomicMax(&rowcand[base + 32 + L], fkey(v1));
        }
    };

    int bsel = 0;
    auto stepc = [](int& ib, int& jp) {
        if (++jp == 256) { if (ib < 63) { ++ib; jp = 4 * ib; } else jp = 255; }
    };

    for (int s = u0; s < uend; ++s) {
        // stage(s) retired: only the EPI atomic(s) are newer (in-order vmcnt)
        asm volatile("s_waitcnt vmcnt(1)" ::: "memory");
        __builtin_amdgcn_s_barrier();
        __builtin_amdgcn_sched_barrier(0);

        if (cib != lib) {                           // rare i-panel change
            int it = cib * 8 + 2 * wid;
            #pragma unroll
            for (int ks = 0; ks < 16; ++ks) {
                bfr0[ks] = F[(it + 0) * 1024 + ks * 64 + lane];
                bfr1[ks] = F[(it + 1) * 1024 + ks * 64 + lane];
            }
            lib = cib;
        }
        const int  mjp = cjp;
        const int  mib = cib;
        const bool mpd = (cjp == cib * 4 + wid);    // this wave's diag unit

        // ---- MFMA: 4 independent chains ----
        const uint4* sb = &sbuf[bsel][0];
        f32x16 c00, c01, c10, c11;
        {
            bf16x8 af0 = *(const bf16x8*)(sb + lane);
            bf16x8 af1 = *(const bf16x8*)(sb + 1024 + lane);
            c00 = __builtin_amdgcn_mfma_f32_32x32x16_bf16(bfr0[0], af0, zc, 0, 0, 0);
            c10 = __builtin_amdgcn_mfma_f32_32x32x16_bf16(bfr1[0], af0, zc, 0, 0, 0);
            c01 = __builtin_amdgcn_mfma_f32_32x32x16_bf16(bfr0[0], af1, zc, 0, 0, 0);
            c11 = __builtin_amdgcn_mfma_f32_32x32x16_bf16(bfr1[0], af1, zc, 0, 0, 0);
        }
        #pragma unroll
        for (int ks = 1; ks < 16; ++ks) {
            bf16x8 af0 = *(const bf16x8*)(sb + ks * 64 + lane);
            bf16x8 af1 = *(const bf16x8*)(sb + 1024 + ks * 64 + lane);
            c00 = __builtin_amdgcn_mfma_f32_32x32x16_bf16(bfr0[ks], af0, c00, 0, 0, 0);
            c10 = __builtin_amdgcn_mfma_f32_32x32x16_bf16(bfr1[ks], af0, c10, 0, 0, 0);
            c01 = __builtin_amdgcn_mfma_f32_32x32x16_bf16(bfr0[ks], af1, c01, 0, 0, 0);
            c11 = __builtin_amdgcn_mfma_f32_32x32x16_bf16(bfr1[ks], af1, c11, 0, 0, 0);
        }

        // ---- stage next pair into the buffer read at iter s-1 ----
        stepc(sib, sjp);
        {
            const uint4* gp = F4 + (size_t)sjp * 2048;
            uint4* dst = &sbuf[bsel ^ 1][0];
            #pragma unroll
            for (int q = 0; q < 8; ++q)
                stage16(gp + q * 256 + tid, dst + q * 256 + wid * 64);
        }

        // ---- EPI: diag mask -> rm accumulate (reg axis) + j-flush (lane) --
        float jm0 = -1e30f, jm1 = -1e30f;
        if (mpd) {                                  // wave-uniform diag path
            #pragma unroll
            for (int r = 0; r < 16; ++r) {
                float v00 = c00[r], v11 = c11[r];
                if (dvalid && r == dreg) { v00 = -1e30f; v11 = -1e30f; }
                rm0[r] = fmaxf(rm0[r], fmaxf(v00, c01[r]));
                rm1[r] = fmaxf(rm1[r], fmaxf(c10[r], v11));
                jm0 = fmaxf(jm0, fmaxf(v00, c10[r]));
                jm1 = fmaxf(jm1, fmaxf(c01[r], v11));
            }
        } else {
            #pragma unroll
            for (int r = 0; r < 16; ++r) {
                rm0[r] = fmaxf(rm0[r], fmaxf(c00[r], c01[r]));
                rm1[r] = fmaxf(rm1[r], fmaxf(c10[r], c11[r]));
                jm0 = fmaxf(jm0, fmaxf(c00[r], c10[r]));
                jm1 = fmaxf(jm1, fmaxf(c01[r], c11[r]));
            }
        }
        jm0 = fmaxf(jm0, __shfl_xor(jm0, 32, 64));  // fold i-halves
        jm1 = fmaxf(jm1, __shfl_xor(jm1, 32, 64));
        float js = hi ? jm1 : jm0;
        atomicMax(&rowcand[mjp * 64 + lane], fkey(js));

        // advance compute cursor; i-panel transition flush
        stepc(cib, cjp);
        if (cib != mib) {
            flush_i(mib);
            #pragma unroll
            for (int r = 0; r < 16; ++r) { rm0[r] = -1e30f; rm1[r] = -1e30f; }
        }
        bsel ^= 1;
    }
    flush_i(lib);   // final flush (no-op -1e30 keys if already flushed)
}

// ---------------- K3: loss epilogue (2-stage, deterministic) --------------
__global__ __launch_bounds__(256) void kloss1(const unsigned* __restrict__ rowcand,
                                              float* __restrict__ partial) {
    int i = blockIdx.x * 256 + threadIdx.x;         // 64 blocks x 256
    unsigned k = rowcand[i];
    unsigned u = (k & 0x80000000u) ? (k ^ 0x80000000u) : ~k;
    float gv = __builtin_bit_cast(float, u);
    float d = sqrtf(fmaxf(2.f - 2.f * gv, 0.f));
    float acc = logf(d + 1e-8f);
    #pragma unroll
    for (int m = 1; m < 64; m <<= 1) acc += __shfl_xor(acc, m, 64);
    __shared__ float p[4];
    int wid = threadIdx.x >> 6, lane = threadIdx.x & 63;
    if (lane == 0) p[wid] = acc;
    __syncthreads();
    if (threadIdx.x == 0)
        partial[blockIdx.x] = (p[0] + p[1]) + (p[2] + p[3]);
}

__global__ __launch_bounds__(64) void kloss2(const float* __restrict__ partial,
                                             float* __restrict__ out) {
    float acc = partial[threadIdx.x];
    #pragma unroll
    for (int m = 1; m < 64; m <<= 1) acc += __shfl_xor(acc, m, 64);
    if (threadIdx.x == 0) out[0] = -acc / (float)NROWS;
}

extern "C" void kernel_launch(void* const* d_in, const int* in_sizes, int n_in,
                              void* d_out, int out_size, void* d_ws, size_t ws_size,
                              hipStream_t stream) {
    const float* x = (const float*)d_in[0];
    float* out = (float*)d_out;
    char* ws = (char*)d_ws;

    uint4*    F       = (uint4*)ws;                                 // 8 MiB
    float*    rn      = (float*)(ws + 8u * 1024u * 1024u);          // 64 KiB
    unsigned* rowcand = (unsigned*)(ws + 8u * 1024u * 1024u + 65536u); // 64 KiB
    float*    partial = (float*)(ws + 8u * 1024u * 1024u + 131072u);   // 256 B

    hipMemsetAsync(rowcand, 0, NROWS * sizeof(unsigned), stream);
    knorm<<<NROWS / 4, 256, 0, stream>>>(x, rn);
    kpack<<<(NROWS * NDIM / 8) / 256, 256, 0, stream>>>(x, rn, F);
    kmax <<<NBLK, 256, 0, stream>>>((const bf16x8*)F, rowcand);
    kloss1<<<64, 256, 0, stream>>>(rowcand, partial);
    kloss2<<<1, 64, 0, stream>>>(partial, out);
}

// Round 12
// 95.147 us; speedup vs baseline: 5.7528x; 1.0549x over previous
//
#include <hip/hip_runtime.h>
#include <hip/hip_bf16.h>
#include <math.h>

// KoLeo loss, MI355X. Fused normalize -> bf16 fragment repack -> MFMA gram
// row-max (never materializes the 16384^2 gram) -> log/mean epilogue.
//
// v12 = v11's pair-unit kernel (proven correct, 232 unified regs, no spill)
// x v9's TWO desynced 4-wave blocks per CU (proven overlap mechanism):
//   - grid 512 (2 blocks/CU): when block A's waves are in EPI/vmcnt-wait,
//     block B's waves feed the MFMA pipe (independent barriers).
//   - unit = 256i x 64j pair, 4 MFMA chains from one acc set, vmcnt(1)
//     counted-wait double-buffer (order: wait/barrier -> MFMA -> stage(next)
//     -> EPI atomics; only EPI atomics are newer than stage at next wait).
//   - T5 setprio around the MFMA cluster (desynced blocks = arbitration room).
//
// F layout (32-row tiles): chunk(t32,ks,lane) = t32*1024 + ks*64 + lane,
//   16B chunk = 8 bf16 of xn[t32*32 + (lane&31)][ks*16 + (lane>>5)*8 .. +7].
// == mfma_f32_32x32x16_bf16 A/B fragment layout -> linear coalesced staging.
// D = mfma(bfr_i, af_j): col=lane&31 -> j_local, row=(r&3)+8(r>>2)+4(lane>>5)
// -> i_local (verified v8-v11).

typedef __attribute__((ext_vector_type(8))) short bf16x8;    // 8 bf16 = 4 VGPR
typedef __attribute__((ext_vector_type(16))) float f32x16;   // 32x32 acc

#define NROWS 16384
#define NDIM  256
#define NBLK  512
// pair-units: ib in [0,64) (256-row i-panel), jp in [4*ib, 256) (64-row j-pair)
// P(ib) = 2*ib*(129-ib); total 8320 units; 16.25 per block.

// ---------------- K0: row 1/norm ----------------
__global__ __launch_bounds__(256) void knorm(const float* __restrict__ x,
                                             float* __restrict__ rn) {
    int wid = threadIdx.x >> 6, lane = threadIdx.x & 63;
    int row = blockIdx.x * 4 + wid;
    const float4* xr = (const float4*)(x + (size_t)row * NDIM);
    float4 v = xr[lane];
    float ss = v.x * v.x + v.y * v.y + v.z * v.z + v.w * v.w;
    #pragma unroll
    for (int m = 1; m < 64; m <<= 1) ss += __shfl_xor(ss, m, 64);
    if (lane == 0) rn[row] = 1.0f / fmaxf(sqrtf(ss), 1e-12f);
}

// ---------------- K1: normalize + pack to 32x32 fragment layout -----------
__device__ inline unsigned bf_rne(float f) {
    union { float f; unsigned u; } c; c.f = f;
    return (c.u + 0x7FFFu + ((c.u >> 16) & 1u)) >> 16;
}
__device__ inline unsigned pack2(float lo, float hi) {
    return bf_rne(lo) | (bf_rne(hi) << 16);
}

__global__ __launch_bounds__(256) void kpack(const float* __restrict__ x,
                                             const float* __restrict__ rn,
                                             uint4* __restrict__ F) {
    int g = blockIdx.x * 256 + threadIdx.x;
    int t32  = g >> 10;
    int rem  = g & 1023;
    int ks   = rem >> 6;
    int lane = rem & 63;
    int row  = t32 * 32 + (lane & 31);
    int kb   = ks * 16 + (lane >> 5) * 8;
    float s = rn[row];
    const float4* xr = (const float4*)(x + (size_t)row * NDIM + kb);
    float4 a = xr[0], b = xr[1];
    uint4 o;
    o.x = pack2(a.x * s, a.y * s);
    o.y = pack2(a.z * s, a.w * s);
    o.z = pack2(b.x * s, b.y * s);
    o.w = pack2(b.z * s, b.w * s);
    F[g] = o;
}

// ---------------- helpers ----------------
__device__ inline void stage16(const uint4* __restrict__ g, const uint4* l) {
    __builtin_amdgcn_global_load_lds(
        (const __attribute__((address_space(1))) unsigned*)g,
        (__attribute__((address_space(3))) unsigned*)l, 16, 0, 0);
}

__device__ inline unsigned fkey(float f) {          // order-preserving key
    unsigned u = __builtin_bit_cast(unsigned, f);
    return (u & 0x80000000u) ? ~u : (u | 0x80000000u);
}

template<int CTRL>                                  // DPP rotate within 16-lane row
__device__ inline float dpp_rot(float x) {
    int xi = __builtin_bit_cast(int, x);
    int yi = __builtin_amdgcn_update_dpp(xi, xi, CTRL, 0xF, 0xF, false);
    return __builtin_bit_cast(float, yi);
}

// ---------------- K2: pipelined symmetric gram + two-sided max ------------
// 512 blocks x 256 threads (4 waves, 2 blocks/CU). Unit = 256i x 64j rows.
__global__ __launch_bounds__(256, 2) void kmax(const bf16x8* __restrict__ F,
                                               unsigned* __restrict__ rowcand) {
    __shared__ uint4 sbuf[2][2048];                 // 2 x 32KB j-pair buffers
    __shared__ uint4 dump[64];                      // pad-load target (dead)

    const int tid  = threadIdx.x;
    const int wid  = tid >> 6;                      // 0..3
    const int lane = tid & 63;
    const int L    = lane & 31;
    const int hi   = lane >> 5;
    const uint4* F4 = (const uint4*)F;

    // XCD-chunked bijective swizzle (512 % 8 == 0)
    const int b    = ((blockIdx.x & 7) << 6) | (blockIdx.x >> 3);
    const int u0   = (b * 65) >> 2;                 // 8320/512 = 16.25
    const int uend = ((b + 1) * 65) >> 2;

    // decode u0 -> (cib, cjp)
    int cib = 0;
    while (2 * (cib + 1) * (129 - (cib + 1)) <= u0) ++cib;
    int cjp = 4 * cib + (u0 - 2 * cib * (129 - cib));

    // hoisted i-fragments: tiles {cib*8 + 2wid, +1}, 128 VGPR
    bf16x8 bfr0[16], bfr1[16];
    int lib = cib;
    {
        int it = cib * 8 + 2 * wid;
        #pragma unroll
        for (int ks = 0; ks < 16; ++ks) {
            bfr0[ks] = F[(it + 0) * 1024 + ks * 64 + lane];
            bfr1[ks] = F[(it + 1) * 1024 + ks * 64 + lane];
        }
    }

    // stage cursor + prologue: stage(u0) [8 loads] + 1 dummy atomic
    int sib = cib, sjp = cjp;
    {
        const uint4* gp = F4 + (size_t)cjp * 2048;
        #pragma unroll
        for (int q = 0; q < 8; ++q)
            stage16(gp + q * 256 + tid, &sbuf[0][q * 256 + wid * 64]);
    }
    atomicMax(&rowcand[0], 0u);                     // uniform vmcnt at iter 0

    float rm0[16], rm1[16];
    #pragma unroll
    for (int r = 0; r < 16; ++r) { rm0[r] = -1e30f; rm1[r] = -1e30f; }

    const bool dvalid = (((L >> 2) & 1) == hi);     // lane holds a diag elem
    const int  dreg   = (L & 3) | ((L >> 3) << 2);  // ...at this acc reg
    const f32x16 zc = {0.f};

    auto flush_i = [&](int fib) {                   // fold rm over j, flush
        #pragma unroll
        for (int r = 0; r < 16; ++r) {
            float a = rm0[r];
            a = fmaxf(a, dpp_rot<0x121>(a));
            a = fmaxf(a, dpp_rot<0x122>(a));
            a = fmaxf(a, dpp_rot<0x124>(a));
            a = fmaxf(a, dpp_rot<0x128>(a));
            rm0[r] = fmaxf(a, __shfl_xor(a, 16, 64));
            float c = rm1[r];
            c = fmaxf(c, dpp_rot<0x121>(c));
            c = fmaxf(c, dpp_rot<0x122>(c));
            c = fmaxf(c, dpp_rot<0x124>(c));
            c = fmaxf(c, dpp_rot<0x128>(c));
            rm1[r] = fmaxf(c, __shfl_xor(c, 16, 64));
        }
        float v0 = rm0[0], v1 = rm1[0];
        #pragma unroll
        for (int r = 1; r < 16; ++r) {
            v0 = (dreg == r) ? rm0[r] : v0;         // lane picks its i-row
            v1 = (dreg == r) ? rm1[r] : v1;
        }
        if (dvalid) {
            int base = fib * 256 + wid * 64;
            atomicMax(&rowcand[base + L],      fkey(v0));
            atomicMax(&rowcand[base + 32 + L], fkey(v1));
        }
    };

    int bsel = 0;
    auto stepc = [](int& ib, int& jp) {
        if (++jp == 256) { if (ib < 63) { ++ib; jp = 4 * ib; } else jp = 255; }
    };

    for (int s = u0; s < uend; ++s) {
        // stage(s) retired: only the EPI atomic(s) are newer (in-order vmcnt)
        asm volatile("s_waitcnt vmcnt(1)" ::: "memory");
        __builtin_amdgcn_s_barrier();
        __builtin_amdgcn_sched_barrier(0);

        if (cib != lib) {                           // rare i-panel change
            int it = cib * 8 + 2 * wid;
            #pragma unroll
            for (int ks = 0; ks < 16; ++ks) {
                bfr0[ks] = F[(it + 0) * 1024 + ks * 64 + lane];
                bfr1[ks] = F[(it + 1) * 1024 + ks * 64 + lane];
            }
            lib = cib;
        }
        const int  mjp = cjp;
        const int  mib = cib;
        const bool mpd = (cjp == cib * 4 + wid);    // this wave's diag unit

        // ---- MFMA: 4 independent chains (setprio'd cluster) ----
        const uint4* sb = &sbuf[bsel][0];
        f32x16 c00, c01, c10, c11;
        __builtin_amdgcn_s_setprio(1);
        {
            bf16x8 af0 = *(const bf16x8*)(sb + lane);
            bf16x8 af1 = *(const bf16x8*)(sb + 1024 + lane);
            c00 = __builtin_amdgcn_mfma_f32_32x32x16_bf16(bfr0[0], af0, zc, 0, 0, 0);
            c10 = __builtin_amdgcn_mfma_f32_32x32x16_bf16(bfr1[0], af0, zc, 0, 0, 0);
            c01 = __builtin_amdgcn_mfma_f32_32x32x16_bf16(bfr0[0], af1, zc, 0, 0, 0);
            c11 = __builtin_amdgcn_mfma_f32_32x32x16_bf16(bfr1[0], af1, zc, 0, 0, 0);
        }
        #pragma unroll
        for (int ks = 1; ks < 16; ++ks) {
            bf16x8 af0 = *(const bf16x8*)(sb + ks * 64 + lane);
            bf16x8 af1 = *(const bf16x8*)(sb + 1024 + ks * 64 + lane);
            c00 = __builtin_amdgcn_mfma_f32_32x32x16_bf16(bfr0[ks], af0, c00, 0, 0, 0);
            c10 = __builtin_amdgcn_mfma_f32_32x32x16_bf16(bfr1[ks], af0, c10, 0, 0, 0);
            c01 = __builtin_amdgcn_mfma_f32_32x32x16_bf16(bfr0[ks], af1, c01, 0, 0, 0);
            c11 = __builtin_amdgcn_mfma_f32_32x32x16_bf16(bfr1[ks], af1, c11, 0, 0, 0);
        }
        __builtin_amdgcn_s_setprio(0);

        // ---- stage next pair into the buffer read at iter s-1 ----
        stepc(sib, sjp);
        {
            const uint4* gp = F4 + (size_t)sjp * 2048;
            uint4* dst = &sbuf[bsel ^ 1][0];
            #pragma unroll
            for (int q = 0; q < 8; ++q)
                stage16(gp + q * 256 + tid, dst + q * 256 + wid * 64);
        }

        // ---- EPI: diag mask -> rm accumulate (reg axis) + j-flush (lane) --
        float jm0 = -1e30f, jm1 = -1e30f;
        if (mpd) {                                  // wave-uniform diag path
            #pragma unroll
            for (int r = 0; r < 16; ++r) {
                float v00 = c00[r], v11 = c11[r];
                if (dvalid && r == dreg) { v00 = -1e30f; v11 = -1e30f; }
                rm0[r] = fmaxf(rm0[r], fmaxf(v00, c01[r]));
                rm1[r] = fmaxf(rm1[r], fmaxf(c10[r], v11));
                jm0 = fmaxf(jm0, fmaxf(v00, c10[r]));
                jm1 = fmaxf(jm1, fmaxf(c01[r], v11));
            }
        } else {
            #pragma unroll
            for (int r = 0; r < 16; ++r) {
                rm0[r] = fmaxf(rm0[r], fmaxf(c00[r], c01[r]));
                rm1[r] = fmaxf(rm1[r], fmaxf(c10[r], c11[r]));
                jm0 = fmaxf(jm0, fmaxf(c00[r], c10[r]));
                jm1 = fmaxf(jm1, fmaxf(c01[r], c11[r]));
            }
        }
        jm0 = fmaxf(jm0, __shfl_xor(jm0, 32, 64));  // fold i-halves
        jm1 = fmaxf(jm1, __shfl_xor(jm1, 32, 64));
        float js = hi ? jm1 : jm0;
        atomicMax(&rowcand[mjp * 64 + lane], fkey(js));

        // advance compute cursor; i-panel transition flush
        stepc(cib, cjp);
        if (cib != mib) {
            flush_i(mib);
            #pragma unroll
            for (int r = 0; r < 16; ++r) { rm0[r] = -1e30f; rm1[r] = -1e30f; }
        }
        bsel ^= 1;
    }
    flush_i(lib);   // final flush (no-op -1e30 keys if already flushed)
}

// ---------------- K3: loss epilogue (2-stage, deterministic) --------------
__global__ __launch_bounds__(256) void kloss1(const unsigned* __restrict__ rowcand,
                                              float* __restrict__ partial) {
    int i = blockIdx.x * 256 + threadIdx.x;         // 64 blocks x 256
    unsigned k = rowcand[i];
    unsigned u = (k & 0x80000000u) ? (k ^ 0x80000000u) : ~k;
    float gv = __builtin_bit_cast(float, u);
    float d = sqrtf(fmaxf(2.f - 2.f * gv, 0.f));
    float acc = logf(d + 1e-8f);
    #pragma unroll
    for (int m = 1; m < 64; m <<= 1) acc += __shfl_xor(acc, m, 64);
    __shared__ float p[4];
    int wid = threadIdx.x >> 6, lane = threadIdx.x & 63;
    if (lane == 0) p[wid] = acc;
    __syncthreads();
    if (threadIdx.x == 0)
        partial[blockIdx.x] = (p[0] + p[1]) + (p[2] + p[3]);
}

__global__ __launch_bounds__(64) void kloss2(const float* __restrict__ partial,
                                             float* __restrict__ out) {
    float acc = partial[threadIdx.x];
    #pragma unroll
    for (int m = 1; m < 64; m <<= 1) acc += __shfl_xor(acc, m, 64);
    if (threadIdx.x == 0) out[0] = -acc / (float)NROWS;
}

extern "C" void kernel_launch(void* const* d_in, const int* in_sizes, int n_in,
                              void* d_out, int out_size, void* d_ws, size_t ws_size,
                              hipStream_t stream) {
    const float* x = (const float*)d_in[0];
    float* out = (float*)d_out;
    char* ws = (char*)d_ws;

    uint4*    F       = (uint4*)ws;                                 // 8 MiB
    float*    rn      = (float*)(ws + 8u * 1024u * 1024u);          // 64 KiB
    unsigned* rowcand = (unsigned*)(ws + 8u * 1024u * 1024u + 65536u); // 64 KiB
    float*    partial = (float*)(ws + 8u * 1024u * 1024u + 131072u);   // 256 B

    hipMemsetAsync(rowcand, 0, NROWS * sizeof(unsigned), stream);
    knorm<<<NROWS / 4, 256, 0, stream>>>(x, rn);
    kpack<<<(NROWS * NDIM / 8) / 256, 256, 0, stream>>>(x, rn, F);
    kmax <<<NBLK, 256, 0, stream>>>((const bf16x8*)F, rowcand);
    kloss1<<<64, 256, 0, stream>>>(rowcand, partial);
    kloss2<<<1, 64, 0, stream>>>(partial, out);
}